// Round 1
// baseline (2399.447 us; speedup 1.0000x reference)
//
#include <hip/hip_runtime.h>
#include <math.h>

#define T 4000
#define C 128
#define BLK 5
#define NB (T/BLK)            // 800
#define BM 64
#define BKT 64
#define NKT ((T + BKT - 1) / BKT)   // 63
#define KSPLIT 9              // 63/9 = 7 k-tiles per y-slice
#define LDSP 132              // padded LDS row stride (floats)

// ---------------- Kernel A: inverse norms ----------------
__global__ __launch_bounds__(64) void norm_kernel(const float* __restrict__ x,
                                                  float* __restrict__ inv_norm) {
    int row = blockIdx.x;            // 0..T-1
    int t = threadIdx.x;             // 0..63
    const float* xr = x + row * C;
    float a = xr[t], b = xr[t + 64];
    float ss = a * a + b * b;
    for (int off = 32; off; off >>= 1) ss += __shfl_xor(ss, off);
    if (t == 0) {
        float n = sqrtf(ss);
        inv_norm[row] = 1.0f / fmaxf(n, 1e-8f);
    }
}

// ---------------- Kernel B: rowsum_i = sum_k exp(xn_i . xn_k) ----------------
__global__ __launch_bounds__(256) void rowsum_kernel(const float* __restrict__ x,
                                                     const float* __restrict__ inv_norm,
                                                     float* __restrict__ rowsum) {
    __shared__ float As[BM][LDSP];
    __shared__ float Bs[BKT][LDSP];
    const int i0 = blockIdx.x * BM;
    const int tid = threadIdx.x;
    const int ty = tid >> 4;        // 0..15  (i-rows: ty + 16*r)
    const int tx = tid & 15;        // 0..15  (k-cols: tx + 16*q)

    // Load A tile (64 rows x 128 cols), normalized, once.
    for (int j = 0; j < 8; ++j) {
        int slot = tid + j * 256;            // 0..2047 (64 rows * 32 float4)
        int row = slot >> 5;
        int col4 = slot & 31;
        int gr = i0 + row;
        float4 v = make_float4(0.f, 0.f, 0.f, 0.f);
        float inv = 0.f;
        if (gr < T) { v = *(const float4*)(x + gr * C + col4 * 4); inv = inv_norm[gr]; }
        float4 w = make_float4(v.x * inv, v.y * inv, v.z * inv, v.w * inv);
        *(float4*)&As[row][col4 * 4] = w;
    }

    float psum[4] = {0.f, 0.f, 0.f, 0.f};

    for (int kt = blockIdx.y; kt < NKT; kt += KSPLIT) {
        const int k0 = kt * BKT;
        __syncthreads();   // (a) A-tile ready on first iter; (b) prior reads of Bs done
        for (int j = 0; j < 8; ++j) {
            int slot = tid + j * 256;
            int row = slot >> 5;
            int col4 = slot & 31;
            int gr = k0 + row;
            float4 v = make_float4(0.f, 0.f, 0.f, 0.f);
            float inv = 0.f;
            if (gr < T) { v = *(const float4*)(x + gr * C + col4 * 4); inv = inv_norm[gr]; }
            float4 w = make_float4(v.x * inv, v.y * inv, v.z * inv, v.w * inv);
            *(float4*)&Bs[row][col4 * 4] = w;
        }
        __syncthreads();

        float acc[4][4];
#pragma unroll
        for (int r = 0; r < 4; ++r)
#pragma unroll
            for (int q = 0; q < 4; ++q) acc[r][q] = 0.f;

#pragma unroll
        for (int c = 0; c < C; c += 4) {
            float4 a[4], b[4];
#pragma unroll
            for (int r = 0; r < 4; ++r) a[r] = *(float4*)&As[ty + 16 * r][c];
#pragma unroll
            for (int q = 0; q < 4; ++q) b[q] = *(float4*)&Bs[tx + 16 * q][c];
#pragma unroll
            for (int r = 0; r < 4; ++r)
#pragma unroll
                for (int q = 0; q < 4; ++q) {
                    acc[r][q] += a[r].x * b[q].x + a[r].y * b[q].y +
                                 a[r].z * b[q].z + a[r].w * b[q].w;
                }
        }

#pragma unroll
        for (int r = 0; r < 4; ++r)
#pragma unroll
            for (int q = 0; q < 4; ++q) {
                int kg = k0 + tx + 16 * q;
                if (kg < T) psum[r] += __expf(acc[r][q]);
            }
    }

    // reduce across the 16 tx lanes sharing each i-row (same wave)
#pragma unroll
    for (int off = 1; off < 16; off <<= 1)
#pragma unroll
        for (int r = 0; r < 4; ++r) psum[r] += __shfl_xor(psum[r], off);

    if (tx == 0) {
#pragma unroll
        for (int r = 0; r < 4; ++r) {
            int gi = i0 + ty + 16 * r;
            if (gi < T) atomicAdd(&rowsum[gi], psum[r]);
        }
    }
}

// ---------------- Kernel C: per-5-block loss ----------------
__global__ __launch_bounds__(64) void loss_kernel(const float* __restrict__ x,
                                                  const float* __restrict__ inv_norm,
                                                  const float* __restrict__ rowsum,
                                                  const int* __restrict__ kuai2p,
                                                  float* __restrict__ out) {
    __shared__ float xs[BLK][C];
    __shared__ float s5[BLK * BLK];
    const int b = blockIdx.x;
    const int base = b * BLK;
    const int t = threadIdx.x;

    for (int j = t; j < BLK * C; j += 64) {
        int r = j / C, cc = j % C;
        xs[r][cc] = x[(base + r) * C + cc] * inv_norm[base + r];
    }
    __syncthreads();

    if (t < 25) {
        int pi = t / 5, pj = t % 5;
        float d = 0.f;
        for (int cc = 0; cc < C; ++cc) d += xs[pi][cc] * xs[pj][cc];
        s5[t] = d;
    }
    __syncthreads();

    float contrib = 0.f;
    if (t < 25) {
        int pi = t / 5, pj = t % 5;
        if (pi != pj) {
            float bsum = 0.f;
#pragma unroll
            for (int j = 0; j < 5; ++j) bsum += __expf(s5[pi * 5 + j]);
            float rs = rowsum[base + pi];
            const float nneg = 2.0f * (float)NB - 2.0f;       // 1598
            const float cfrac = nneg / (float)(T - BLK);      // 1598/3995
            float negE = cfrac * (rs - bsum);                 // expected neg_sum
            float sij = s5[t];
            float pos = __expf(sij);
            contrib = sij - __logf(negE + pos);               // log(pos/(neg+pos))
        }
    }
    for (int off = 32; off; off >>= 1) contrib += __shfl_xor(contrib, off);
    if (t == 0) {
        int k = *kuai2p;
        float scale = -1.0f / ((float)NB * (float)k * (float)(k - 1));
        atomicAdd(out, contrib * scale);
    }
}

extern "C" void kernel_launch(void* const* d_in, const int* in_sizes, int n_in,
                              void* d_out, int out_size, void* d_ws, size_t ws_size,
                              hipStream_t stream) {
    const float* x = (const float*)d_in[0];
    const int* kuai2 = (const int*)d_in[1];
    float* out = (float*)d_out;

    float* inv_norm = (float*)d_ws;          // T floats
    float* rowsum = inv_norm + T;            // T floats

    hipMemsetAsync(rowsum, 0, T * sizeof(float), stream);
    hipMemsetAsync(out, 0, sizeof(float), stream);

    norm_kernel<<<T, 64, 0, stream>>>(x, inv_norm);

    dim3 grid((T + BM - 1) / BM, KSPLIT);
    rowsum_kernel<<<grid, 256, 0, stream>>>(x, inv_norm, rowsum);

    loss_kernel<<<NB, 64, 0, stream>>>(x, inv_norm, rowsum, kuai2, out);
}

// Round 2
// 60.343 us; speedup vs baseline: 39.7633x; 39.7633x over previous
//
#include <hip/hip_runtime.h>
#include <hip/hip_bf16.h>
#include <math.h>

#define T 4000
#define C 128
#define BLK 5
#define NB (T/BLK)            // 800
#define KTILES (T/16)         // 250 k-tiles of 16 rows
#define KS 16                 // k-split (grid.y)

typedef short bf16x8 __attribute__((ext_vector_type(8)));
typedef float f32x4 __attribute__((ext_vector_type(4)));

// ---------------- Kernel A: inverse norms + bf16 normalized rows ----------------
__global__ __launch_bounds__(64) void norm_kernel(const float* __restrict__ x,
                                                  float* __restrict__ inv_norm,
                                                  __hip_bfloat16* __restrict__ xnb) {
    int row = blockIdx.x;            // 0..T-1
    int t = threadIdx.x;             // 0..63
    const float* xr = x + row * C;
    float a = xr[t], b = xr[t + 64];
    float ss = a * a + b * b;
    for (int off = 32; off; off >>= 1) ss += __shfl_xor(ss, off);
    float inv = 1.0f / fmaxf(sqrtf(ss), 1e-8f);
    xnb[row * C + t]      = __float2bfloat16(a * inv);
    xnb[row * C + t + 64] = __float2bfloat16(b * inv);
    if (t == 0) inv_norm[row] = inv;
}

// ---------------- Kernel B: rowsum_i = sum_k exp(xn_i . xn_k), bf16 MFMA ----------------
// Wave-level: each wave owns 16 i-rows (A frags held in regs), streams k-tiles of
// 16 rows as B frags directly from global (L1/L2-resident), 4x mfma 16x16x32 per
// k-tile (C=128), exp + accumulate into 4 per-lane row-sum registers.
// A frag: lane holds row (lane&15), 8 contiguous channels at kc*32+(lane>>4)*8.
// B frag: identical pattern (col j = lane&15 maps to xn row k0+j).
// C/D frag: col = lane&15 (k-col), row = (lane>>4)*4 + reg (i-row).  [m89-verified]
__global__ __launch_bounds__(256) void rowsum_mfma(const __hip_bfloat16* __restrict__ xnb,
                                                   float* __restrict__ rowsum) {
    const int wid  = threadIdx.x >> 6;      // 0..3
    const int lane = threadIdx.x & 63;
    const int i0 = blockIdx.x * 64 + wid * 16;
    if (i0 >= T) return;                    // T%16==0 so whole waves drop out

    const int r  = lane & 15;
    const int ko = (lane >> 4) * 8;         // 0,8,16,24

    bf16x8 afrag[4];
    const __hip_bfloat16* arow = xnb + (size_t)(i0 + r) * C;
#pragma unroll
    for (int kc = 0; kc < 4; ++kc)
        afrag[kc] = *(const bf16x8*)(arow + kc * 32 + ko);

    f32x4 rsum = {0.f, 0.f, 0.f, 0.f};

    for (int kt = blockIdx.y; kt < KTILES; kt += KS) {
        const __hip_bfloat16* brow = xnb + (size_t)(kt * 16 + r) * C;
        f32x4 acc = {0.f, 0.f, 0.f, 0.f};
#pragma unroll
        for (int kc = 0; kc < 4; ++kc) {
            bf16x8 bfrag = *(const bf16x8*)(brow + kc * 32 + ko);
            acc = __builtin_amdgcn_mfma_f32_16x16x32_bf16(afrag[kc], bfrag, acc, 0, 0, 0);
        }
#pragma unroll
        for (int j = 0; j < 4; ++j) rsum[j] += __expf(acc[j]);
    }

    // reduce over the 16 k-cols (low 4 lane bits); lanes sharing lane>>4 hold same i-rows
#pragma unroll
    for (int off = 1; off < 16; off <<= 1)
#pragma unroll
        for (int j = 0; j < 4; ++j) rsum[j] += __shfl_xor(rsum[j], off);

    if ((lane & 15) == 0) {
        const int ibase = i0 + (lane >> 4) * 4;
#pragma unroll
        for (int j = 0; j < 4; ++j) atomicAdd(&rowsum[ibase + j], rsum[j]);
    }
}

// ---------------- Kernel C: per-5-block loss (fp32, exact pos/bsum) ----------------
__global__ __launch_bounds__(64) void loss_kernel(const float* __restrict__ x,
                                                  const float* __restrict__ inv_norm,
                                                  const float* __restrict__ rowsum,
                                                  const int* __restrict__ kuai2p,
                                                  float* __restrict__ out) {
    __shared__ float xs[BLK][C];
    __shared__ float s5[BLK * BLK];
    const int b = blockIdx.x;
    const int base = b * BLK;
    const int t = threadIdx.x;

    for (int j = t; j < BLK * C; j += 64) {
        int r = j / C, cc = j % C;
        xs[r][cc] = x[(base + r) * C + cc] * inv_norm[base + r];
    }
    __syncthreads();

    if (t < 25) {
        int pi = t / 5, pj = t % 5;
        float d = 0.f;
        for (int cc = 0; cc < C; ++cc) d += xs[pi][cc] * xs[pj][cc];
        s5[t] = d;
    }
    __syncthreads();

    float contrib = 0.f;
    if (t < 25) {
        int pi = t / 5, pj = t % 5;
        if (pi != pj) {
            float bsum = 0.f;
#pragma unroll
            for (int j = 0; j < 5; ++j) bsum += __expf(s5[pi * 5 + j]);
            float rs = rowsum[base + pi];
            const float nneg = 2.0f * (float)NB - 2.0f;       // 1598
            const float cfrac = nneg / (float)(T - BLK);      // 1598/3995
            float negE = cfrac * (rs - bsum);                 // expected neg_sum
            float sij = s5[t];
            float pos = __expf(sij);
            contrib = sij - __logf(negE + pos);               // log(pos/(neg+pos))
        }
    }
    for (int off = 32; off; off >>= 1) contrib += __shfl_xor(contrib, off);
    if (t == 0) {
        int k = *kuai2p;
        float scale = -1.0f / ((float)NB * (float)k * (float)(k - 1));
        atomicAdd(out, contrib * scale);
    }
}

extern "C" void kernel_launch(void* const* d_in, const int* in_sizes, int n_in,
                              void* d_out, int out_size, void* d_ws, size_t ws_size,
                              hipStream_t stream) {
    const float* x = (const float*)d_in[0];
    const int* kuai2 = (const int*)d_in[1];
    float* out = (float*)d_out;

    float* inv_norm = (float*)d_ws;                       // T floats
    float* rowsum   = inv_norm + T;                       // T floats
    __hip_bfloat16* xnb = (__hip_bfloat16*)(rowsum + T);  // T*C bf16

    hipMemsetAsync(rowsum, 0, T * sizeof(float), stream);
    hipMemsetAsync(out, 0, sizeof(float), stream);

    norm_kernel<<<T, 64, 0, stream>>>(x, inv_norm, xnb);

    dim3 grid((T + 63) / 64, KS);
    rowsum_mfma<<<grid, 256, 0, stream>>>(xnb, rowsum);

    loss_kernel<<<NB, 64, 0, stream>>>(x, inv_norm, rowsum, kuai2, out);
}